// Round 6
// baseline (170.598 us; speedup 1.0000x reference)
//
#include <hip/hip_runtime.h>
#include <stdint.h>

typedef __bf16 bf16;
typedef __attribute__((ext_vector_type(8))) __bf16 bf16x8;
typedef __attribute__((ext_vector_type(4))) __bf16 bf16x4;
typedef __attribute__((ext_vector_type(4))) float f32x4;
typedef __attribute__((ext_vector_type(16))) float f32x16;
typedef __attribute__((ext_vector_type(2))) unsigned u32x2;

#define AS1 __attribute__((address_space(1)))
#define AS3 __attribute__((address_space(3)))

#if __has_builtin(__builtin_amdgcn_permlane32_swap)
#define HAVE_PLSWAP 1
#else
#define HAVE_PLSWAP 0
#endif

__device__ __forceinline__ float ex2(float x) {
#if __has_builtin(__builtin_amdgcn_exp2f)
  return __builtin_amdgcn_exp2f(x);
#else
  return exp2f(x);
#endif
}

__device__ __forceinline__ void barrier_f() {
  asm volatile("" ::: "memory");
  __builtin_amdgcn_s_barrier();
  asm volatile("" ::: "memory");
}

template <int N>
__device__ __forceinline__ void waitVm() {
  if constexpr (N == 0) asm volatile("s_waitcnt vmcnt(0)" ::: "memory");
  else if constexpr (N == 1) asm volatile("s_waitcnt vmcnt(1)" ::: "memory");
  else if constexpr (N == 2) asm volatile("s_waitcnt vmcnt(2)" ::: "memory");
  else if constexpr (N == 4) asm volatile("s_waitcnt vmcnt(4)" ::: "memory");
  else if constexpr (N == 6) asm volatile("s_waitcnt vmcnt(6)" ::: "memory");
  else if constexpr (N == 8) asm volatile("s_waitcnt vmcnt(8)" ::: "memory");
  else static_assert(N == 0, "unsupported vmcnt");
  __builtin_amdgcn_sched_barrier(0);
}

// cross-half 32-lane swap: r0 = {a_lo, b_lo}, r1 = {a_hi, b_hi}
__device__ __forceinline__ u32x2 swap32(uint32_t a, uint32_t b, int hh) {
#if HAVE_PLSWAP
  (void)hh;
  return __builtin_amdgcn_permlane32_swap(a, b, false, false);
#else
  u32x2 r;
  r[0] = hh ? __shfl_xor(b, 32) : a;
  r[1] = hh ? b : __shfl_xor(a, 32);
  return r;
#endif
}

// ---------------------------------------------------------------------------
// Merged prologue (R2 version): x fp32->bf16 cast + both weight relayouts.
// ---------------------------------------------------------------------------
template <int K>
__device__ __forceinline__ void relay_body(const float* __restrict__ W,
                                           bf16* __restrict__ Bp, int t) {
  const int off = t * 8;
  const int sub = (off & 511) >> 3;
  const int n = sub & 15, khi = sub >> 4;
  const int blk = off >> 9;
  const int kblk = blk & ((K >> 5) - 1);
  const int nblk = blk >> (31 - __builtin_clz(K >> 5));
  const float* src = W + (size_t)(nblk * 16 + n) * K + kblk * 32 + khi * 8;
  float4 a = *reinterpret_cast<const float4*>(src);
  float4 b = *reinterpret_cast<const float4*>(src + 4);
  bf16x8 o = { (bf16)a.x, (bf16)a.y, (bf16)a.z, (bf16)a.w,
               (bf16)b.x, (bf16)b.y, (bf16)b.z, (bf16)b.w };
  *reinterpret_cast<bf16x8*>(Bp + off) = o;
}

__global__ __launch_bounds__(256) void prologue_kernel(
    const float* __restrict__ x, bf16* __restrict__ xb,
    const float* __restrict__ wqkv, bf16* __restrict__ BpQ,
    const float* __restrict__ wo, bf16* __restrict__ BpO) {
  const int blk = blockIdx.x;
  if (blk < 8192) {                       // x cast: 2097152 float4s
    const int i = blk * 256 + threadIdx.x;
    float4 v = reinterpret_cast<const float4*>(x)[i];
    bf16x4 r = { (bf16)v.x, (bf16)v.y, (bf16)v.z, (bf16)v.w };
    reinterpret_cast<bf16x4*>(xb)[i] = r;
  } else if (blk < 11264) {               // wqkv relayout (3072 blocks)
    relay_body<2048>(wqkv, BpQ, (blk - 8192) * 256 + threadIdx.x);
  } else {                                // wo relayout (2048 blocks)
    relay_body<2048>(wo, BpO, (blk - 11264) * 256 + threadIdx.x);
  }
}

// ---------------------------------------------------------------------------
// QKV GEMM (exact R2/R5 config, BN=384, NR=3, grid 512): UNCHANGED.
// ---------------------------------------------------------------------------
template <int BN, typename OutT, bool FUSE, int MINW>
__global__ __launch_bounds__(512, MINW) void gemmfc2(
    const bf16* __restrict__ A, const bf16* __restrict__ Bp,
    OutT* __restrict__ C, const float* __restrict__ fc,
    bf16* __restrict__ Qd, bf16* __restrict__ Kd, bf16* __restrict__ Vd,
    int N, int K) {
  constexpr int WTN = BN / 8;       // wave cols (48)
  constexpr int NR = WTN / 16;      // n-tiles per wave (3)
  constexpr int NBF = 2 * NR;       // B loads per tile (6)
  constexpr int ABUF = 64 * 128;    // 8 KiB per A buffer
  __shared__ char smem[2 * ABUF];
  AS3 char* sm3 = (AS3 char*)smem;

  const int tid = threadIdx.x;
  const int w = tid >> 6, lane = tid & 63;
  const int fr = lane & 15, fq = lane >> 4;
  const int xorA = (fr & 7) << 4;

  const int orig = blockIdx.x;
  const int cpx = (int)gridDim.x >> 3;
  const int wgid = (orig & 7) * cpx + (orig >> 3);
  const int bm = (wgid & 63) * 64;
  const int bn = (wgid >> 6) * BN;
  const int KB = K >> 5;
  const int nbBase = (bn >> 4) + w * NR;

  f32x4 acc[4][NR] = {};

  auto stageA = [&](int t, int buf) {
    AS3 char* db = sm3 + buf * ABUF;
    const int row = tid >> 3;               // 0..63
    const int kslot = (tid & 7) ^ (row & 7);
    __builtin_amdgcn_global_load_lds(
        (const AS1 void*)(A + (size_t)(bm + row) * K + t * 64 + kslot * 8),
        (AS3 void*)(db + w * 1024), 16, 0, 0);
  };

  stageA(0, 0);

  const int NT = K >> 6;
  for (int t = 0; t < NT; ++t) {
    const int cb = t & 1;
    const bool pf = (t + 1 < NT);
    bf16x8 bF[NR][2];
#pragma unroll
    for (int ni = 0; ni < NR; ++ni)
#pragma unroll
      for (int ks = 0; ks < 2; ++ks)
        bF[ni][ks] = *reinterpret_cast<const bf16x8*>(
            Bp + ((size_t)(nbBase + ni) * KB + t * 2 + ks) * 512 + lane * 8);
    waitVm<NBF>();   // drain stageA(t); B stays in flight
    barrier_f();
    if (pf) stageA(t + 1, cb ^ 1);
    const char* cbA = smem + cb * ABUF;
    bf16x8 aF[2][2];
#pragma unroll
    for (int mi = 0; mi < 2; ++mi)
#pragma unroll
      for (int ks = 0; ks < 2; ++ks)
        aF[mi][ks] = *reinterpret_cast<const bf16x8*>(
            cbA + (mi * 16 + fr) * 128 + ((ks * 64 + fq * 16) ^ xorA));
    if (pf) waitVm<1>(); else waitVm<0>();  // drain B; keep stage in flight
#pragma unroll
    for (int mp = 0; mp < 2; ++mp) {
      if (mp > 0) {
#pragma unroll
        for (int mi = 0; mi < 2; ++mi)
#pragma unroll
          for (int ks = 0; ks < 2; ++ks)
            aF[mi][ks] = *reinterpret_cast<const bf16x8*>(
                cbA + (32 + mi * 16 + fr) * 128 + ((ks * 64 + fq * 16) ^ xorA));
      }
      __builtin_amdgcn_s_setprio(1);
#pragma unroll
      for (int ks = 0; ks < 2; ++ks)
#pragma unroll
        for (int mi = 0; mi < 2; ++mi)
#pragma unroll
          for (int ni = 0; ni < NR; ++ni)
            acc[mp * 2 + mi][ni] = __builtin_amdgcn_mfma_f32_16x16x32_bf16(
                aF[mi][ks], bF[ni][ks], acc[mp * 2 + mi][ni], 0, 0, 0);
      __builtin_amdgcn_s_setprio(0);
    }
  }

  if constexpr (FUSE) {
    barrier_f();                       // all waves done with A tiles
    float* smF = (float*)smem;         // 64 rows x 64 floats = 16 KB exact
    {
      const float* fsrc = fc + (size_t)(bm & 1023) * 64;
#pragma unroll
      for (int k = 0; k < 2; ++k)
        reinterpret_cast<float4*>(smF)[tid + k * 512] =
            reinterpret_cast<const float4*>(fsrc)[tid + k * 512];
    }
    __syncthreads();
    const float QSCALE = 0.125f * 1.4426950408889634f;
    const int par = fr & 1;  // odd lane holds x1 of the rotary pair
#pragma unroll
    for (int ni = 0; ni < NR; ++ni) {
      const int col = bn + w * WTN + ni * 16 + fr;  // e index, uniform /16
#pragma unroll
      for (int mi = 0; mi < 4; ++mi) {
        const int sl = mi * 16 + fq * 4;            // local token row
        const int row0 = bm + sl;
        const int bb = row0 >> 10, s0 = row0 & 1023;
        if (col < 2560) {
          const int e = (col < 2048) ? col : col - 2048;
          const int d = e & 63, hq = e >> 6;
          const int dbase = d & ~1;
          bf16* dst = (col < 2048)
              ? Qd + (((size_t)(bb * 32 + hq)) * 1024 + s0) * 64 + d
              : Kd + (((size_t)(bb * 8 + hq)) * 1024 + s0) * 64 + d;
#pragma unroll
          for (int j = 0; j < 4; ++j) {
            float v = acc[mi][ni][j];
            float pv = __shfl_xor(v, 1);
            float2 csn = *reinterpret_cast<const float2*>(
                &smF[(sl + j) * 64 + dbase]);   // one ds_read_b64
            float r = par ? (v * csn.x + pv * csn.y)
                          : (v * csn.x - pv * csn.y);
            if (col < 2048) r *= QSCALE;
            dst[(size_t)j * 64] = (bf16)r;
          }
        } else {
          const int e = col - 2560, d = e & 63, hv = e >> 6;
          bf16x4 pk4;
#pragma unroll
          for (int j = 0; j < 4; ++j) pk4[j] = (bf16)acc[mi][ni][j];
          *reinterpret_cast<bf16x4*>(
              Vd + (((size_t)(bb * 8 + hv)) * 64 + d) * 1024 + s0) = pk4;
        }
      }
    }
  } else {
    const int cbn = bn + w * WTN + fr;
#pragma unroll
    for (int mi = 0; mi < 4; ++mi) {
      const int rb = bm + mi * 16 + fq * 4;
#pragma unroll
      for (int ni = 0; ni < NR; ++ni)
#pragma unroll
        for (int j = 0; j < 4; ++j)
          C[(size_t)(rb + j) * N + cbn + ni * 16] = (OutT)acc[mi][ni][j];
    }
  }
}

// ---------------------------------------------------------------------------
// WO GEMM, R6: 32x32x16 MFMA, 2m x 4n wave partition. Each wave reads only
// 32 A-rows -> 4 ds_read_b128/iter (halves the LDS-pipe time that the R5
// ledger showed was 73% of the iteration slot). BM=64, BN=256, grid 512
// (2 blocks/CU). A-fragment layout (row=lane&31, k=s*16+(lane>>5)*8) is the
// attn kernel's verified QK^T pattern, same XOR swizzle arithmetic.
// ---------------------------------------------------------------------------
__global__ __launch_bounds__(512, 4) void gemm_wo32(
    const bf16* __restrict__ A, const bf16* __restrict__ Bp,
    float* __restrict__ C, int N, int K) {
  constexpr int ABUF = 64 * 128;    // 8 KiB per A buffer
  __shared__ char smem[2 * ABUF];
  AS3 char* sm3 = (AS3 char*)smem;

  const int tid = threadIdx.x;
  const int w = tid >> 6, lane = tid & 63;
  const int qn = lane & 31, hh = lane >> 5;
  const int wr = w >> 2, wc = w & 3;      // 2m x 4n wave grid

  const int orig = blockIdx.x;
  const int cpx = (int)gridDim.x >> 3;
  const int wgid = (orig & 7) * cpx + (orig >> 3);
  const int bm = (wgid & 63) * 64;
  const int bn = (wgid >> 6) * 256;
  const int KB = K >> 5;
  // 16-col tile base for this lane's B reads: col = bn + wc*64 + nt*32 + qn
  const int nbB = (bn >> 4) + wc * 4 + ((lane >> 4) & 1);

  f32x16 acc2[2] = {};

  auto stageA = [&](int t, int buf) {
    AS3 char* db = sm3 + buf * ABUF;
    const int row = tid >> 3;               // 0..63
    const int kslot = (tid & 7) ^ (row & 7);
    __builtin_amdgcn_global_load_lds(
        (const AS1 void*)(A + (size_t)(bm + row) * K + t * 64 + kslot * 8),
        (AS3 void*)(db + w * 1024), 16, 0, 0);
  };

  stageA(0, 0);

  const int xorR = (qn & 7) << 4;         // row-XOR for A reads (row&7 == qn&7)
  const int NT = K >> 6;
  for (int t = 0; t < NT; ++t) {
    const int cb = t & 1;
    const bool pf = (t + 1 < NT);
    // B fragments: col = bn + wc*64 + nt*32 + qn, k = s*16 + hh*8 (+t*64)
    bf16x8 bF2[2][4];
#pragma unroll
    for (int nt = 0; nt < 2; ++nt)
#pragma unroll
      for (int s = 0; s < 4; ++s)
        bF2[nt][s] = *reinterpret_cast<const bf16x8*>(
            Bp + ((size_t)(nbB + nt * 2) * KB + t * 2 + (s >> 1)) * 512 +
            ((s & 1) * 2 + hh) * 128 + (lane & 15) * 8);
    waitVm<8>();     // drain stageA(t); 8 B loads stay in flight
    barrier_f();
    if (pf) stageA(t + 1, cb ^ 1);
    const char* cbA = smem + cb * ABUF;
    // A fragments: row = wr*32 + qn, k = s*16 + hh*8 (chunk (2s+hh) ^ row&7)
    bf16x8 aF2[4];
#pragma unroll
    for (int s = 0; s < 4; ++s)
      aF2[s] = *reinterpret_cast<const bf16x8*>(
          cbA + (wr * 32 + qn) * 128 + (((2 * s + hh) << 4) ^ xorR));
    if (pf) waitVm<1>(); else waitVm<0>();  // drain B; keep stage in flight
    __builtin_amdgcn_s_setprio(1);
#pragma unroll
    for (int s = 0; s < 4; ++s)
#pragma unroll
      for (int nt = 0; nt < 2; ++nt)
        acc2[nt] = __builtin_amdgcn_mfma_f32_32x32x16_bf16(
            aF2[s], bF2[nt][s], acc2[nt], 0, 0, 0);
    __builtin_amdgcn_s_setprio(0);
  }

  // C-write: row = bm + wr*32 + (r&3)+8*(r>>2)+4*hh, col = bn + wc*64 + nt*32 + qn
#pragma unroll
  for (int nt = 0; nt < 2; ++nt) {
    const int col = bn + wc * 64 + nt * 32 + qn;
#pragma unroll
    for (int r = 0; r < 16; ++r) {
      const int row = bm + wr * 32 + (r & 3) + 8 * (r >> 2) + 4 * hh;
      C[(size_t)row * N + col] = acc2[nt][r];
    }
  }
}

// ---------------------------------------------------------------------------
// Causal GQA flash attention (unchanged from R2 uniform-work version).
// ---------------------------------------------------------------------------
__global__ __launch_bounds__(256, 4) void attn_kernel(const bf16* __restrict__ Q,
                                                      const bf16* __restrict__ K,
                                                      const bf16* __restrict__ Vt,
                                                      bf16* __restrict__ Y) {
  __shared__ bf16 smem[25600];  // 32 KB staging (2x8K K + 2x8K V) + 18 KB epi
  char* sb = (char*)smem;
  AS3 char* sA = (AS3 char*)smem;

  // fid = ((j*4 + b)*4 + hl)*8 + hkv   (fid&7 = hkv -> XCD co-location)
  const int fid = blockIdx.x;
  const int hkv = fid & 7;
  const int hl = (fid >> 3) & 3;
  const int b = (fid >> 5) & 3;
  const int j = (fid >> 7) & 3;
  const int h = hkv * 4 + hl;

  const int w = threadIdx.x >> 6, lane = threadIdx.x & 63;
  const int qn = lane & 31;
  const int hh = lane >> 5;
  const int srow = lane >> 3;                      // 0..7
  const int scb = (((lane & 7) ^ srow) << 4);
  const int xsw = (qn & 7) << 4;

  const bf16* Qh = Q + ((size_t)(b * 32 + h)) * 65536;
  const char* kB = (const char*)(K + ((size_t)(b * 8 + hkv)) * 65536);
  const char* vB = (const char*)(Vt + ((size_t)(b * 8 + hkv)) * 65536);

  const int nchA = 2 * j + 2;          // chunks of tile j
  const int TOT = 18;                  // nchA + (16 - 2j) for all j

  auto stage = [&](int ci, int buf) {
    const int kc = ci << 6;
    const int bo = buf * 8192;
#pragma unroll
    for (int i = 0; i < 2; ++i) {
      const int row = i * 32 + 8 * w + srow;       // 0..63
      __builtin_amdgcn_global_load_lds(
          (const AS1 void*)(kB + (size_t)(kc + row) * 128 + scb),
          (AS3 void*)(sA + bo + i * 4096 + w * 1024), 16, 0, 0);
      __builtin_amdgcn_global_load_lds(
          (const AS1 void*)(vB + (size_t)row * 2048 + kc * 2 + scb),
          (AS3 void*)(sA + 16384 + bo + i * 4096 + w * 1024), 16, 0, 0);
    }
  };

  auto applyMask = [&](f32x16* st, int kc, int qg) {
#pragma unroll
    for (int mt = 0; mt < 2; ++mt)
#pragma unroll
      for (int r = 0; r < 16; ++r) {
        int kv = kc + mt * 32 + (r & 3) + 8 * (r >> 2) + 4 * hh;
        if (kv > qg) st[mt][r] = -3e38f;
      }
  };

  union F32U { float f; uint32_t u; };
  union W64 { uint32_t u; bf16 b[2]; };

  // ---- tile state ----
  int tq0 = j * 128 + w * 32;
  int maskFrom = tq0 >> 6;
  bf16x8 qf[4];
#pragma unroll
  for (int s = 0; s < 4; ++s)
    qf[s] = *reinterpret_cast<const bf16x8*>(
        &Qh[(size_t)(tq0 + qn) * 64 + s * 16 + hh * 8]);
  f32x16 O[2] = {};
  float mrow = -3e38f, lrow = 0.f;

  // per-wave, barrier-free epilogue (transpose area is wave-private)
  auto epilogue = [&]() {
    float inv = 1.f / lrow;
    bf16* Ytw = smem + 16384 + w * 2304;   // 32 x 72, above staging
#pragma unroll
    for (int dt = 0; dt < 2; ++dt)
#pragma unroll
      for (int r = 0; r < 16; ++r) {
        int d = dt * 32 + (r & 3) + 8 * (r >> 2) + 4 * hh;
        Ytw[qn * 72 + d] = (bf16)(O[dt][r] * inv);
      }
    asm volatile("s_waitcnt lgkmcnt(0)" ::: "memory");  // own-wave ds_write -> ds_read
    const int qr = lane >> 1, c0 = (lane & 1) * 32;
    bf16* yout = Y + ((size_t)(b * 1024 + tq0 - w * 32 + (w * 32) + qr)) * 2048 + h * 64 + c0;
#pragma unroll
    for (int i = 0; i < 4; ++i)
      *reinterpret_cast<bf16x8*>(&yout[i * 8]) =
          *reinterpret_cast<const bf16x8*>(&Ytw[qr * 72 + c0 + i * 8]);
  };

  stage(0, 0);

  for (int s = 0; s < TOT; ++s) {
    const int cur = s & 1;
    const int c = (s < nchA) ? s : s - nchA;
    if (s + 1 < TOT) {
      stage((s + 1 < nchA) ? s + 1 : s + 1 - nchA, cur ^ 1);
      waitVm<4>();                    // my stage(s) (and any qf) landed
    } else {
      waitVm<0>();
    }
    barrier_f();                      // everyone's stage(s) landed
    const int kc = c << 6;
    const char* Kc = sb + cur * 8192;
    const char* Vc = sb + 16384 + cur * 8192;

    bf16x8 kf[2][4];
#pragma unroll
    for (int mt = 0; mt < 2; ++mt)
#pragma unroll
      for (int si = 0; si < 4; ++si)
        kf[mt][si] = *reinterpret_cast<const bf16x8*>(
            Kc + (qn + 32 * mt) * 128 + ((32 * si + 16 * hh) ^ xsw));
    f32x16 st[2] = {};
#pragma unroll
    for (int mt = 0; mt < 2; ++mt)
#pragma unroll
      for (int si = 0; si < 4; ++si)
        st[mt] = __builtin_amdgcn_mfma_f32_32x32x16_bf16(kf[mt][si], qf[si], st[mt], 0, 0, 0);
    if (c >= maskFrom) applyMask(st, kc, tq0 + qn);
    // ---- online softmax, defer-max (T13) ----
    float t16[16];
#pragma unroll
    for (int i = 0; i < 16; ++i) t16[i] = fmaxf(st[0][i], st[1][i]);
#pragma unroll
    for (int off = 8; off >= 1; off >>= 1)
#pragma unroll
      for (int i = 0; i < off; ++i) t16[i] = fmaxf(t16[i], t16[i + off]);
    F32U fm; fm.f = t16[0];
    u32x2 rm = swap32(fm.u, fm.u, hh);
    F32U m0, m1; m0.u = rm[0]; m1.u = rm[1];
    float mx = fmaxf(m0.f, m1.f);
    if (!__all(mx - mrow <= 8.f)) {
      float mnew = fmaxf(mrow, mx);
      float alpha = ex2(mrow - mnew);
      lrow *= alpha;
#pragma unroll
      for (int dt = 0; dt < 2; ++dt)
#pragma unroll
        for (int r = 0; r < 16; ++r) O[dt][r] *= alpha;
      mrow = mnew;
    }
    W64 pk[2][8];
    float ps[16];
#pragma unroll
    for (int t = 0; t < 2; ++t)
#pragma unroll
      for (int wi = 0; wi < 8; ++wi) {
        float p0 = ex2(st[t][2 * wi] - mrow);
        float p1 = ex2(st[t][2 * wi + 1] - mrow);
        ps[t * 8 + wi] = p0 + p1;
        pk[t][wi].b[0] = (bf16)p0;
        pk[t][wi].b[1] = (bf16)p1;
      }
#pragma unroll
    for (int off = 8; off >= 1; off >>= 1)
#pragma unroll
      for (int i = 0; i < off; ++i) ps[i] += ps[i + off];
    F32U fs; fs.f = ps[0];
    u32x2 rs = swap32(fs.u, fs.u, hh);
    F32U s0, s1; s0.u = rs[0]; s1.u = rs[1];
    lrow += s0.f + s1.f;
    // ---- O^T += V^T . P ----
#pragma unroll
    for (int si = 0; si < 4; ++si) {
      const int t = si >> 1, a0 = 4 * (si & 1);
      u32x2 rA = swap32(pk[t][a0 + 0].u, pk[t][a0 + 2].u, hh);
      u32x2 rB = swap32(pk[t][a0 + 1].u, pk[t][a0 + 3].u, hh);
      union BF { uint32_t u[4]; bf16x8 v; } bfrag;
      bfrag.u[0] = rA[0];
      bfrag.u[1] = rB[0];
      bfrag.u[2] = rA[1];
      bfrag.u[3] = rB[1];
#pragma unroll
      for (int dt = 0; dt < 2; ++dt) {
        bf16x8 vf = *reinterpret_cast<const bf16x8*>(
            Vc + (qn + 32 * dt) * 128 + ((32 * si + 16 * hh) ^ xsw));
        O[dt] = __builtin_amdgcn_mfma_f32_32x32x16_bf16(vf, bfrag.v, O[dt], 0, 0, 0);
      }
    }
    barrier_f();                      // all waves done reading buf cur

    if (s == nchA - 1) {
      // ---- tile switch: prefetch new Q frags, then epilogue (hides lat) ----
      const int nq0 = (7 - j) * 128 + w * 32;
      bf16x8 nqf[4];
#pragma unroll
      for (int si = 0; si < 4; ++si)
        nqf[si] = *reinterpret_cast<const bf16x8*>(
            &Qh[(size_t)(nq0 + qn) * 64 + si * 16 + hh * 8]);
      epilogue();                      // writes tile A output (uses tq0)
      tq0 = nq0;
      maskFrom = tq0 >> 6;
#pragma unroll
      for (int si = 0; si < 4; ++si) qf[si] = nqf[si];
#pragma unroll
      for (int dt = 0; dt < 2; ++dt)
#pragma unroll
        for (int r = 0; r < 16; ++r) O[dt][r] = 0.f;
      mrow = -3e38f;
      lrow = 0.f;
    }
  }

  epilogue();                          // tile B output
}

// ---------------------------------------------------------------------------
extern "C" void kernel_launch(void* const* d_in, const int* in_sizes, int n_in,
                              void* d_out, int out_size, void* d_ws, size_t ws_size,
                              hipStream_t stream) {
  const float* x    = (const float*)d_in[0];  // [4,1024,2048]
  const float* fc   = (const float*)d_in[1];  // [1024,32,2]
  // d_in[2] = causal mask: structural, ignored
  const float* wqkv = (const float*)d_in[3];  // [3072,2048]
  const float* wo   = (const float*)d_in[4];  // [2048,2048]
  float* out = (float*)d_out;                 // [4096,2048] fp32

  char* ws = (char*)d_ws;
  const size_t MB = 1u << 20;
  bf16* xb    = (bf16*)(ws);            // 16 MB  [4096][2048]
  bf16* BpQ   = (bf16*)(ws + 16 * MB);  // 12 MB  wqkv fragment-linear
  bf16* BpO   = (bf16*)(ws + 28 * MB);  //  8 MB  wo fragment-linear
  bf16* Qr    = (bf16*)(ws + 60 * MB);  // 16 MB  [4][32][1024][64]
  bf16* Kr    = (bf16*)(ws + 76 * MB);  //  4 MB  [4][8][1024][64]
  bf16* Vt    = (bf16*)(ws + 80 * MB);  //  4 MB  [4][8][64][1024]
  bf16* Y     = (bf16*)(ws + 84 * MB);  // 16 MB  [4096][2048]

  prologue_kernel<<<13312, 256, 0, stream>>>(x, xb, wqkv, BpQ, wo, BpO);

  // QKV GEMM with fused RoPE/split epilogue (writes Qr, Kr, Vt directly)
  gemmfc2<384, bf16, true, 4><<<512, 512, 0, stream>>>(
      xb, BpQ, (bf16*)nullptr, fc, Qr, Kr, Vt, 3072, 2048);

  attn_kernel<<<512, 256, 0, stream>>>(Qr, Kr, Vt, Y);

  // WO GEMM: 32x32 MFMA, BN=256, grid 512 (2 blocks/CU)
  gemm_wo32<<<512, 512, 0, stream>>>(Y, BpO, out, 2048, 2048);
}

// Round 7
// 145.219 us; speedup vs baseline: 1.1748x; 1.1748x over previous
//
#include <hip/hip_runtime.h>
#include <stdint.h>

typedef __bf16 bf16;
typedef __attribute__((ext_vector_type(8))) __bf16 bf16x8;
typedef __attribute__((ext_vector_type(4))) __bf16 bf16x4;
typedef __attribute__((ext_vector_type(4))) float f32x4;
typedef __attribute__((ext_vector_type(16))) float f32x16;
typedef __attribute__((ext_vector_type(2))) unsigned u32x2;

#define AS1 __attribute__((address_space(1)))
#define AS3 __attribute__((address_space(3)))

#if __has_builtin(__builtin_amdgcn_permlane32_swap)
#define HAVE_PLSWAP 1
#else
#define HAVE_PLSWAP 0
#endif

__device__ __forceinline__ float ex2(float x) {
#if __has_builtin(__builtin_amdgcn_exp2f)
  return __builtin_amdgcn_exp2f(x);
#else
  return exp2f(x);
#endif
}

__device__ __forceinline__ void barrier_f() {
  asm volatile("" ::: "memory");
  __builtin_amdgcn_s_barrier();
  asm volatile("" ::: "memory");
}

template <int N>
__device__ __forceinline__ void waitVm() {
  if constexpr (N == 0) asm volatile("s_waitcnt vmcnt(0)" ::: "memory");
  else if constexpr (N == 1) asm volatile("s_waitcnt vmcnt(1)" ::: "memory");
  else if constexpr (N == 2) asm volatile("s_waitcnt vmcnt(2)" ::: "memory");
  else if constexpr (N == 4) asm volatile("s_waitcnt vmcnt(4)" ::: "memory");
  else if constexpr (N == 6) asm volatile("s_waitcnt vmcnt(6)" ::: "memory");
  else if constexpr (N == 8) asm volatile("s_waitcnt vmcnt(8)" ::: "memory");
  else static_assert(N == 0, "unsupported vmcnt");
  __builtin_amdgcn_sched_barrier(0);
}

// cross-half 32-lane swap: r0 = {a_lo, b_lo}, r1 = {a_hi, b_hi}
__device__ __forceinline__ u32x2 swap32(uint32_t a, uint32_t b, int hh) {
#if HAVE_PLSWAP
  (void)hh;
  return __builtin_amdgcn_permlane32_swap(a, b, false, false);
#else
  u32x2 r;
  r[0] = hh ? __shfl_xor(b, 32) : a;
  r[1] = hh ? b : __shfl_xor(a, 32);
  return r;
#endif
}

// ---------------------------------------------------------------------------
// Fragment relayout helper (shared by prologue and attn's wo-relay prefix).
// ---------------------------------------------------------------------------
template <int K>
__device__ __forceinline__ void relay_body(const float* __restrict__ W,
                                           bf16* __restrict__ Bp, int t) {
  const int off = t * 8;
  const int sub = (off & 511) >> 3;
  const int n = sub & 15, khi = sub >> 4;
  const int blk = off >> 9;
  const int kblk = blk & ((K >> 5) - 1);
  const int nblk = blk >> (31 - __builtin_clz(K >> 5));
  const float* src = W + (size_t)(nblk * 16 + n) * K + kblk * 32 + khi * 8;
  float4 a = *reinterpret_cast<const float4*>(src);
  float4 b = *reinterpret_cast<const float4*>(src + 4);
  bf16x8 o = { (bf16)a.x, (bf16)a.y, (bf16)a.z, (bf16)a.w,
               (bf16)b.x, (bf16)b.y, (bf16)b.z, (bf16)b.w };
  *reinterpret_cast<bf16x8*>(Bp + off) = o;
}

// ---------------------------------------------------------------------------
// Prologue: x fp32->bf16 cast + wqkv relayout. (wo relayout moved into the
// attn kernel as a serial prefix — attn is latency-bound with HBM slack.)
// ---------------------------------------------------------------------------
__global__ __launch_bounds__(256) void prologue_kernel(
    const float* __restrict__ x, bf16* __restrict__ xb,
    const float* __restrict__ wqkv, bf16* __restrict__ BpQ) {
  const int blk = blockIdx.x;
  if (blk < 8192) {                       // x cast: 2097152 float4s
    const int i = blk * 256 + threadIdx.x;
    float4 v = reinterpret_cast<const float4*>(x)[i];
    bf16x4 r = { (bf16)v.x, (bf16)v.y, (bf16)v.z, (bf16)v.w };
    reinterpret_cast<bf16x4*>(xb)[i] = r;
  } else {                                // wqkv relayout (3072 blocks)
    relay_body<2048>(wqkv, BpQ, (blk - 8192) * 256 + threadIdx.x);
  }
}

// ---------------------------------------------------------------------------
// All-N flat-B GEMM (exact R2 config): BN=384 QKV | BN=256 WO, grid 512,
// MINW=4. Known structural ceiling ~900 TF (m97 2-barrier schedule);
// duration is stall-bound and invariant to per-slot MFMA count.
// ---------------------------------------------------------------------------
template <int BN, typename OutT, bool FUSE, int MINW>
__global__ __launch_bounds__(512, MINW) void gemmfc2(
    const bf16* __restrict__ A, const bf16* __restrict__ Bp,
    OutT* __restrict__ C, const float* __restrict__ fc,
    bf16* __restrict__ Qd, bf16* __restrict__ Kd, bf16* __restrict__ Vd,
    int N, int K) {
  constexpr int WTN = BN / 8;       // wave cols (48 | 32)
  constexpr int NR = WTN / 16;      // n-tiles per wave (3 | 2)
  constexpr int NBF = 2 * NR;       // B loads per tile (6 | 4)
  constexpr int ABUF = 64 * 128;    // 8 KiB per A buffer
  __shared__ char smem[2 * ABUF];
  AS3 char* sm3 = (AS3 char*)smem;

  const int tid = threadIdx.x;
  const int w = tid >> 6, lane = tid & 63;
  const int fr = lane & 15, fq = lane >> 4;
  const int xorA = (fr & 7) << 4;

  const int orig = blockIdx.x;
  const int cpx = (int)gridDim.x >> 3;
  const int wgid = (orig & 7) * cpx + (orig >> 3);
  const int bm = (wgid & 63) * 64;
  const int bn = (wgid >> 6) * BN;
  const int KB = K >> 5;
  const int nbBase = (bn >> 4) + w * NR;

  f32x4 acc[4][NR] = {};

  auto stageA = [&](int t, int buf) {
    AS3 char* db = sm3 + buf * ABUF;
    const int row = tid >> 3;               // 0..63
    const int kslot = (tid & 7) ^ (row & 7);
    __builtin_amdgcn_global_load_lds(
        (const AS1 void*)(A + (size_t)(bm + row) * K + t * 64 + kslot * 8),
        (AS3 void*)(db + w * 1024), 16, 0, 0);
  };

  stageA(0, 0);

  const int NT = K >> 6;
  for (int t = 0; t < NT; ++t) {
    const int cb = t & 1;
    const bool pf = (t + 1 < NT);
    bf16x8 bF[NR][2];
#pragma unroll
    for (int ni = 0; ni < NR; ++ni)
#pragma unroll
      for (int ks = 0; ks < 2; ++ks)
        bF[ni][ks] = *reinterpret_cast<const bf16x8*>(
            Bp + ((size_t)(nbBase + ni) * KB + t * 2 + ks) * 512 + lane * 8);
    waitVm<NBF>();   // drain stageA(t); B stays in flight
    barrier_f();
    if (pf) stageA(t + 1, cb ^ 1);
    const char* cbA = smem + cb * ABUF;
    bf16x8 aF[2][2];
#pragma unroll
    for (int mi = 0; mi < 2; ++mi)
#pragma unroll
      for (int ks = 0; ks < 2; ++ks)
        aF[mi][ks] = *reinterpret_cast<const bf16x8*>(
            cbA + (mi * 16 + fr) * 128 + ((ks * 64 + fq * 16) ^ xorA));
    if (pf) waitVm<1>(); else waitVm<0>();  // drain B; keep stage in flight
#pragma unroll
    for (int mp = 0; mp < 2; ++mp) {
      if (mp > 0) {
#pragma unroll
        for (int mi = 0; mi < 2; ++mi)
#pragma unroll
          for (int ks = 0; ks < 2; ++ks)
            aF[mi][ks] = *reinterpret_cast<const bf16x8*>(
                cbA + (32 + mi * 16 + fr) * 128 + ((ks * 64 + fq * 16) ^ xorA));
      }
      __builtin_amdgcn_s_setprio(1);
#pragma unroll
      for (int ks = 0; ks < 2; ++ks)
#pragma unroll
        for (int mi = 0; mi < 2; ++mi)
#pragma unroll
          for (int ni = 0; ni < NR; ++ni)
            acc[mp * 2 + mi][ni] = __builtin_amdgcn_mfma_f32_16x16x32_bf16(
                aF[mi][ks], bF[ni][ks], acc[mp * 2 + mi][ni], 0, 0, 0);
      __builtin_amdgcn_s_setprio(0);
    }
  }

  if constexpr (FUSE) {
    barrier_f();                       // all waves done with A tiles
    float* smF = (float*)smem;         // 64 rows x 64 floats = 16 KB exact
    {
      const float* fsrc = fc + (size_t)(bm & 1023) * 64;
#pragma unroll
      for (int k = 0; k < 2; ++k)
        reinterpret_cast<float4*>(smF)[tid + k * 512] =
            reinterpret_cast<const float4*>(fsrc)[tid + k * 512];
    }
    __syncthreads();
    const float QSCALE = 0.125f * 1.4426950408889634f;
    const int par = fr & 1;  // odd lane holds x1 of the rotary pair
#pragma unroll
    for (int ni = 0; ni < NR; ++ni) {
      const int col = bn + w * WTN + ni * 16 + fr;  // e index, uniform /16
#pragma unroll
      for (int mi = 0; mi < 4; ++mi) {
        const int sl = mi * 16 + fq * 4;            // local token row
        const int row0 = bm + sl;
        const int bb = row0 >> 10, s0 = row0 & 1023;
        if (col < 2560) {
          const int e = (col < 2048) ? col : col - 2048;
          const int d = e & 63, hq = e >> 6;
          const int dbase = d & ~1;
          bf16* dst = (col < 2048)
              ? Qd + (((size_t)(bb * 32 + hq)) * 1024 + s0) * 64 + d
              : Kd + (((size_t)(bb * 8 + hq)) * 1024 + s0) * 64 + d;
#pragma unroll
          for (int j = 0; j < 4; ++j) {
            float v = acc[mi][ni][j];
            float pv = __shfl_xor(v, 1);
            float2 csn = *reinterpret_cast<const float2*>(
                &smF[(sl + j) * 64 + dbase]);   // one ds_read_b64
            float r = par ? (v * csn.x + pv * csn.y)
                          : (v * csn.x - pv * csn.y);
            if (col < 2048) r *= QSCALE;
            dst[(size_t)j * 64] = (bf16)r;
          }
        } else {
          const int e = col - 2560, d = e & 63, hv = e >> 6;
          bf16x4 pk4;
#pragma unroll
          for (int j = 0; j < 4; ++j) pk4[j] = (bf16)acc[mi][ni][j];
          *reinterpret_cast<bf16x4*>(
              Vd + (((size_t)(bb * 8 + hv)) * 64 + d) * 1024 + s0) = pk4;
        }
      }
    }
  } else {
    const int cbn = bn + w * WTN + fr;
#pragma unroll
    for (int mi = 0; mi < 4; ++mi) {
      const int rb = bm + mi * 16 + fq * 4;
#pragma unroll
      for (int ni = 0; ni < NR; ++ni)
#pragma unroll
        for (int j = 0; j < 4; ++j)
          C[(size_t)(rb + j) * N + cbn + ni * 16] = (OutT)acc[mi][ni][j];
    }
  }
}

// ---------------------------------------------------------------------------
// Causal GQA flash attention (R2 uniform-work version) + wo-relay PREFIX:
// each of 512 blocks relays 16 KB of wo->BpO via 4 plain relay_body calls
// per thread before any attn work. Plain loads/stores, compiler-managed
// waits; the loop's keep-newest-N vmcnt waits conservatively drain any
// stragglers, so there is no ordering assumption (unlike R3's in-loop fold).
// ---------------------------------------------------------------------------
__global__ __launch_bounds__(256, 4) void attn_kernel(const bf16* __restrict__ Q,
                                                      const bf16* __restrict__ K,
                                                      const bf16* __restrict__ Vt,
                                                      bf16* __restrict__ Y,
                                                      const float* __restrict__ woSrc,
                                                      bf16* __restrict__ BpOd) {
  __shared__ bf16 smem[25600];  // 32 KB staging (2x8K K + 2x8K V) + 18 KB epi
  char* sb = (char*)smem;
  AS3 char* sA = (AS3 char*)smem;

  // fid = ((j*4 + b)*4 + hl)*8 + hkv   (fid&7 = hkv -> XCD co-location)
  const int fid = blockIdx.x;

  // ---- wo relayout prefix: 512 blocks x 256 thr x 4 units x 8 elems = 8MB
  {
    const int tbase = fid * 1024 + (int)threadIdx.x * 4;
#pragma unroll
    for (int k = 0; k < 4; ++k)
      relay_body<2048>(woSrc, BpOd, tbase + k);
  }

  const int hkv = fid & 7;
  const int hl = (fid >> 3) & 3;
  const int b = (fid >> 5) & 3;
  const int j = (fid >> 7) & 3;
  const int h = hkv * 4 + hl;

  const int w = threadIdx.x >> 6, lane = threadIdx.x & 63;
  const int qn = lane & 31;
  const int hh = lane >> 5;
  const int srow = lane >> 3;                      // 0..7
  const int scb = (((lane & 7) ^ srow) << 4);
  const int xsw = (qn & 7) << 4;

  const bf16* Qh = Q + ((size_t)(b * 32 + h)) * 65536;
  const char* kB = (const char*)(K + ((size_t)(b * 8 + hkv)) * 65536);
  const char* vB = (const char*)(Vt + ((size_t)(b * 8 + hkv)) * 65536);

  const int nchA = 2 * j + 2;          // chunks of tile j
  const int TOT = 18;                  // nchA + (16 - 2j) for all j

  auto stage = [&](int ci, int buf) {
    const int kc = ci << 6;
    const int bo = buf * 8192;
#pragma unroll
    for (int i = 0; i < 2; ++i) {
      const int row = i * 32 + 8 * w + srow;       // 0..63
      __builtin_amdgcn_global_load_lds(
          (const AS1 void*)(kB + (size_t)(kc + row) * 128 + scb),
          (AS3 void*)(sA + bo + i * 4096 + w * 1024), 16, 0, 0);
      __builtin_amdgcn_global_load_lds(
          (const AS1 void*)(vB + (size_t)row * 2048 + kc * 2 + scb),
          (AS3 void*)(sA + 16384 + bo + i * 4096 + w * 1024), 16, 0, 0);
    }
  };

  auto applyMask = [&](f32x16* st, int kc, int qg) {
#pragma unroll
    for (int mt = 0; mt < 2; ++mt)
#pragma unroll
      for (int r = 0; r < 16; ++r) {
        int kv = kc + mt * 32 + (r & 3) + 8 * (r >> 2) + 4 * hh;
        if (kv > qg) st[mt][r] = -3e38f;
      }
  };

  union F32U { float f; uint32_t u; };
  union W64 { uint32_t u; bf16 b[2]; };

  // ---- tile state ----
  int tq0 = j * 128 + w * 32;
  int maskFrom = tq0 >> 6;
  bf16x8 qf[4];
#pragma unroll
  for (int s = 0; s < 4; ++s)
    qf[s] = *reinterpret_cast<const bf16x8*>(
        &Qh[(size_t)(tq0 + qn) * 64 + s * 16 + hh * 8]);
  f32x16 O[2] = {};
  float mrow = -3e38f, lrow = 0.f;

  // per-wave, barrier-free epilogue (transpose area is wave-private)
  auto epilogue = [&]() {
    float inv = 1.f / lrow;
    bf16* Ytw = smem + 16384 + w * 2304;   // 32 x 72, above staging
#pragma unroll
    for (int dt = 0; dt < 2; ++dt)
#pragma unroll
      for (int r = 0; r < 16; ++r) {
        int d = dt * 32 + (r & 3) + 8 * (r >> 2) + 4 * hh;
        Ytw[qn * 72 + d] = (bf16)(O[dt][r] * inv);
      }
    asm volatile("s_waitcnt lgkmcnt(0)" ::: "memory");  // own-wave ds_write -> ds_read
    const int qr = lane >> 1, c0 = (lane & 1) * 32;
    bf16* yout = Y + ((size_t)(b * 1024 + tq0 - w * 32 + (w * 32) + qr)) * 2048 + h * 64 + c0;
#pragma unroll
    for (int i = 0; i < 4; ++i)
      *reinterpret_cast<bf16x8*>(&yout[i * 8]) =
          *reinterpret_cast<const bf16x8*>(&Ytw[qr * 72 + c0 + i * 8]);
  };

  stage(0, 0);

  for (int s = 0; s < TOT; ++s) {
    const int cur = s & 1;
    const int c = (s < nchA) ? s : s - nchA;
    if (s + 1 < TOT) {
      stage((s + 1 < nchA) ? s + 1 : s + 1 - nchA, cur ^ 1);
      waitVm<4>();                    // my stage(s) (and any qf) landed
    } else {
      waitVm<0>();
    }
    barrier_f();                      // everyone's stage(s) landed
    const int kc = c << 6;
    const char* Kc = sb + cur * 8192;
    const char* Vc = sb + 16384 + cur * 8192;

    bf16x8 kf[2][4];
#pragma unroll
    for (int mt = 0; mt < 2; ++mt)
#pragma unroll
      for (int si = 0; si < 4; ++si)
        kf[mt][si] = *reinterpret_cast<const bf16x8*>(
            Kc + (qn + 32 * mt) * 128 + ((32 * si + 16 * hh) ^ xsw));
    f32x16 st[2] = {};
#pragma unroll
    for (int mt = 0; mt < 2; ++mt)
#pragma unroll
      for (int si = 0; si < 4; ++si)
        st[mt] = __builtin_amdgcn_mfma_f32_32x32x16_bf16(kf[mt][si], qf[si], st[mt], 0, 0, 0);
    if (c >= maskFrom) applyMask(st, kc, tq0 + qn);
    // ---- online softmax, defer-max (T13) ----
    float t16[16];
#pragma unroll
    for (int i = 0; i < 16; ++i) t16[i] = fmaxf(st[0][i], st[1][i]);
#pragma unroll
    for (int off = 8; off >= 1; off >>= 1)
#pragma unroll
      for (int i = 0; i < off; ++i) t16[i] = fmaxf(t16[i], t16[i + off]);
    F32U fm; fm.f = t16[0];
    u32x2 rm = swap32(fm.u, fm.u, hh);
    F32U m0, m1; m0.u = rm[0]; m1.u = rm[1];
    float mx = fmaxf(m0.f, m1.f);
    if (!__all(mx - mrow <= 8.f)) {
      float mnew = fmaxf(mrow, mx);
      float alpha = ex2(mrow - mnew);
      lrow *= alpha;
#pragma unroll
      for (int dt = 0; dt < 2; ++dt)
#pragma unroll
        for (int r = 0; r < 16; ++r) O[dt][r] *= alpha;
      mrow = mnew;
    }
    W64 pk[2][8];
    float ps[16];
#pragma unroll
    for (int t = 0; t < 2; ++t)
#pragma unroll
      for (int wi = 0; wi < 8; ++wi) {
        float p0 = ex2(st[t][2 * wi] - mrow);
        float p1 = ex2(st[t][2 * wi + 1] - mrow);
        ps[t * 8 + wi] = p0 + p1;
        pk[t][wi].b[0] = (bf16)p0;
        pk[t][wi].b[1] = (bf16)p1;
      }
#pragma unroll
    for (int off = 8; off >= 1; off >>= 1)
#pragma unroll
      for (int i = 0; i < off; ++i) ps[i] += ps[i + off];
    F32U fs; fs.f = ps[0];
    u32x2 rs = swap32(fs.u, fs.u, hh);
    F32U s0, s1; s0.u = rs[0]; s1.u = rs[1];
    lrow += s0.f + s1.f;
    // ---- O^T += V^T . P ----
#pragma unroll
    for (int si = 0; si < 4; ++si) {
      const int t = si >> 1, a0 = 4 * (si & 1);
      u32x2 rA = swap32(pk[t][a0 + 0].u, pk[t][a0 + 2].u, hh);
      u32x2 rB = swap32(pk[t][a0 + 1].u, pk[t][a0 + 3].u, hh);
      union BF { uint32_t u[4]; bf16x8 v; } bfrag;
      bfrag.u[0] = rA[0];
      bfrag.u[1] = rB[0];
      bfrag.u[2] = rA[1];
      bfrag.u[3] = rB[1];
#pragma unroll
      for (int dt = 0; dt < 2; ++dt) {
        bf16x8 vf = *reinterpret_cast<const bf16x8*>(
            Vc + (qn + 32 * dt) * 128 + ((32 * si + 16 * hh) ^ xsw));
        O[dt] = __builtin_amdgcn_mfma_f32_32x32x16_bf16(vf, bfrag.v, O[dt], 0, 0, 0);
      }
    }
    barrier_f();                      // all waves done reading buf cur

    if (s == nchA - 1) {
      // ---- tile switch: prefetch new Q frags, then epilogue (hides lat) ----
      const int nq0 = (7 - j) * 128 + w * 32;
      bf16x8 nqf[4];
#pragma unroll
      for (int si = 0; si < 4; ++si)
        nqf[si] = *reinterpret_cast<const bf16x8*>(
            &Qh[(size_t)(nq0 + qn) * 64 + si * 16 + hh * 8]);
      epilogue();                      // writes tile A output (uses tq0)
      tq0 = nq0;
      maskFrom = tq0 >> 6;
#pragma unroll
      for (int si = 0; si < 4; ++si) qf[si] = nqf[si];
#pragma unroll
      for (int dt = 0; dt < 2; ++dt)
#pragma unroll
        for (int r = 0; r < 16; ++r) O[dt][r] = 0.f;
      mrow = -3e38f;
      lrow = 0.f;
    }
  }

  epilogue();                          // tile B output
}

// ---------------------------------------------------------------------------
extern "C" void kernel_launch(void* const* d_in, const int* in_sizes, int n_in,
                              void* d_out, int out_size, void* d_ws, size_t ws_size,
                              hipStream_t stream) {
  const float* x    = (const float*)d_in[0];  // [4,1024,2048]
  const float* fc   = (const float*)d_in[1];  // [1024,32,2]
  // d_in[2] = causal mask: structural, ignored
  const float* wqkv = (const float*)d_in[3];  // [3072,2048]
  const float* wo   = (const float*)d_in[4];  // [2048,2048]
  float* out = (float*)d_out;                 // [4096,2048] fp32

  char* ws = (char*)d_ws;
  const size_t MB = 1u << 20;
  bf16* xb    = (bf16*)(ws);            // 16 MB  [4096][2048]
  bf16* BpQ   = (bf16*)(ws + 16 * MB);  // 12 MB  wqkv fragment-linear
  bf16* BpO   = (bf16*)(ws + 28 * MB);  //  8 MB  wo fragment-linear
  bf16* Qr    = (bf16*)(ws + 60 * MB);  // 16 MB  [4][32][1024][64]
  bf16* Kr    = (bf16*)(ws + 76 * MB);  //  4 MB  [4][8][1024][64]
  bf16* Vt    = (bf16*)(ws + 80 * MB);  //  4 MB  [4][8][64][1024]
  bf16* Y     = (bf16*)(ws + 84 * MB);  // 16 MB  [4096][2048]

  prologue_kernel<<<11264, 256, 0, stream>>>(x, xb, wqkv, BpQ);

  // QKV GEMM with fused RoPE/split epilogue (writes Qr, Kr, Vt directly)
  gemmfc2<384, bf16, true, 4><<<512, 512, 0, stream>>>(
      xb, BpQ, (bf16*)nullptr, fc, Qr, Kr, Vt, 3072, 2048);

  // attn (+ wo relayout prefix feeding the WO GEMM below)
  attn_kernel<<<512, 256, 0, stream>>>(Qr, Kr, Vt, Y, wo, BpO);

  // WO GEMM (exact R2 config): BN=256, grid 512
  gemmfc2<256, float, false, 4><<<512, 512, 0, stream>>>(
      Y, BpO, out, nullptr, nullptr, nullptr, nullptr, 2048, 2048);
}